// Round 1
// baseline (530.237 us; speedup 1.0000x reference)
//
#include <hip/hip_runtime.h>
#include <hip/hip_bf16.h>
#include <math.h>

#define N 8192
#define D 128
#define NC 10

// ---------------- ws layout (bytes) ----------------
// 0      : u_idx  int[N]          (compacted unknown row indices)
// 32768  : labs   char[N]         (label 0..9, -1 = unknown)
// 40960  : n      float[N]        (||x_i||^2)
// 73728  : aArr   float[N]        (a_i, unknown rows only)
// 106496 : dinv   float[N]        (1/denom_i, unknown rows only)
// 139264 : h      float[N*2]
// 204800 : gpre   float[N*2]      (sparse part of adj@h, unknown rows only)
// 270336 : part1  float[64*33]
// 278784 : part2  float[64*20]
// 283904 : scal   float[64]  slots: 0..19 clsH[c][e]; 20,21 uSum; 22..31 counts;
//                             32 nuF; 33 fc; 34,35 kSum; 40..59 centroids
// 284160 : nuCnt  int

__global__ void k_prep(const float* __restrict__ x, const float* __restrict__ ohm,
                       const float* __restrict__ W, const float* __restrict__ bb,
                       char* __restrict__ labs, float* __restrict__ nArr,
                       float* __restrict__ h, int* __restrict__ u_idx,
                       int* __restrict__ nuCnt) {
    int gt = blockIdx.x * blockDim.x + threadIdx.x;
    int wid = gt >> 6;           // one wave per row
    int lane = gt & 63;
    if (wid >= N) return;
    const float2* xr = (const float2*)(x + (size_t)wid * D);
    float2 xv = xr[lane];
    float2 w0 = ((const float2*)W)[lane];
    float2 w1 = ((const float2*)(W + D))[lane];
    float nn = xv.x * xv.x + xv.y * xv.y;
    float h0 = xv.x * w0.x + xv.y * w0.y;
    float h1 = xv.x * w1.x + xv.y * w1.y;
    for (int off = 32; off; off >>= 1) {
        nn += __shfl_down(nn, off);
        h0 += __shfl_down(h0, off);
        h1 += __shfl_down(h1, off);
    }
    if (lane == 0) {
        nArr[wid] = nn;
        h[wid * 2 + 0] = h0 + bb[0];
        h[wid * 2 + 1] = h1 + bb[1];
        const float* orow = ohm + (size_t)wid * NC;
        int lab = -1;
        for (int c = 0; c < NC; ++c) {
            if (orow[c] > 0.5f) { lab = c; break; }
        }
        labs[wid] = (char)lab;
        if (lab < 0) {
            int slot = atomicAdd(nuCnt, 1);
            u_idx[slot] = wid;
        }
    }
}

// deterministic class-wise sums of h + counts
__global__ void k_sumA(const char* __restrict__ labs, const float* __restrict__ h,
                       float* __restrict__ part1) {
    __shared__ float L[256][33];
    int t = threadIdx.x;
    for (int s = 0; s < 33; ++s) L[t][s] = 0.f;
    int row = blockIdx.x * 256 + t;   // 64*256 = 16384 covers N
    if (row < N) {
        int lab = labs[row];
        float h0 = h[row * 2], h1 = h[row * 2 + 1];
        if (lab >= 0) {
            L[t][lab * 2] = h0; L[t][lab * 2 + 1] = h1; L[t][22 + lab] = 1.f;
        } else {
            L[t][20] = h0; L[t][21] = h1; L[t][32] = 1.f;
        }
    }
    __syncthreads();
    if (t < 33) {
        float s = 0.f;
        for (int i = 0; i < 256; ++i) s += L[i][t];
        part1[blockIdx.x * 33 + t] = s;
    }
}

__global__ void k_sumB(const float* __restrict__ part1, float* __restrict__ scal) {
    int t = threadIdx.x;
    if (t < 33) {
        float s = 0.f;
        for (int i = 0; i < 64; ++i) s += part1[i * 33 + t];
        scal[t] = s;
    }
    __syncthreads();
    if (t == 0) {
        float k0 = 0.f, k1 = 0.f;
        for (int c = 0; c < NC; ++c) { k0 += scal[c * 2]; k1 += scal[c * 2 + 1]; }
        scal[34] = k0; scal[35] = k1;                 // sum of h over known rows
        scal[33] = 1.0f / fmaxf(scal[32], 1.0f);      // fc
    }
}

// D2c[a][j] = ||x[u_idx[a]] - x[j]||^2 for all j, a < nu. Written to adj region (scratch).
__global__ void k_gemm(const float* __restrict__ x, const float* __restrict__ nArr,
                       const int* __restrict__ u_idx, const int* __restrict__ nuCnt,
                       float* __restrict__ scratch) {
    __shared__ float As[64][D + 1];
    __shared__ float Bs[64][D + 1];
    __shared__ int Ai[64];
    int nu = *nuCnt;
    int a0 = blockIdx.y * 64;
    if (a0 >= nu) return;
    int j0 = blockIdx.x * 64;
    int t = threadIdx.x;
    for (int c = t; c < 64 * 32; c += 256) {
        int r = c >> 5, c4 = c & 31;
        int a = a0 + r;
        int orig = (a < nu) ? u_idx[a] : u_idx[0];
        if (c4 == 0) Ai[r] = (a < nu) ? orig : -1;
        float4 av = ((const float4*)(x + (size_t)orig * D))[c4];
        As[r][c4 * 4 + 0] = av.x; As[r][c4 * 4 + 1] = av.y;
        As[r][c4 * 4 + 2] = av.z; As[r][c4 * 4 + 3] = av.w;
        float4 bv = ((const float4*)(x + (size_t)(j0 + r) * D))[c4];
        Bs[r][c4 * 4 + 0] = bv.x; Bs[r][c4 * 4 + 1] = bv.y;
        Bs[r][c4 * 4 + 2] = bv.z; Bs[r][c4 * 4 + 3] = bv.w;
    }
    __syncthreads();
    int tx = t & 15, ty = t >> 4;
    float acc[4][4];
#pragma unroll
    for (int m = 0; m < 4; ++m)
#pragma unroll
        for (int q = 0; q < 4; ++q) acc[m][q] = 0.f;
#pragma unroll 4
    for (int k = 0; k < D; ++k) {
        float a4[4], b4[4];
#pragma unroll
        for (int m = 0; m < 4; ++m) a4[m] = As[ty * 4 + m][k];
#pragma unroll
        for (int q = 0; q < 4; ++q) b4[q] = Bs[tx * 4 + q][k];
#pragma unroll
        for (int m = 0; m < 4; ++m)
#pragma unroll
            for (int q = 0; q < 4; ++q) acc[m][q] += a4[m] * b4[q];
    }
#pragma unroll
    for (int m = 0; m < 4; ++m) {
        int ar = ty * 4 + m;
        int orig = Ai[ar];
        if (orig < 0) continue;
        float ni = nArr[orig];
        float4 o;
        int jb = j0 + tx * 4;
        float v0 = fmaxf(ni + nArr[jb + 0] - 2.f * acc[m][0], 0.f);
        float v1 = fmaxf(ni + nArr[jb + 1] - 2.f * acc[m][1], 0.f);
        float v2 = fmaxf(ni + nArr[jb + 2] - 2.f * acc[m][2], 0.f);
        float v3 = fmaxf(ni + nArr[jb + 3] - 2.f * acc[m][3], 0.f);
        if (orig == jb + 0) v0 = 0.f;
        if (orig == jb + 1) v1 = 0.f;
        if (orig == jb + 2) v2 = 0.f;
        if (orig == jb + 3) v3 = 0.f;
        o.x = v0; o.y = v1; o.z = v2; o.w = v3;
        *((float4*)(scratch + (size_t)(a0 + ar) * N + jb)) = o;
    }
}

// per unknown row: exact kth order statistic via bitwise binary search (regs-resident row)
__global__ void k_select(const float* __restrict__ scratch, const int* __restrict__ u_idx,
                         const int* __restrict__ nuCnt, const int* __restrict__ spars,
                         float* __restrict__ aArr, float* __restrict__ dinv) {
    int nu = *nuCnt;
    int a = blockIdx.x;
    if (a >= nu) return;
    int k = *spars;
    int need = k + 1;
    int t = threadIdx.x;
    const float4* rp = (const float4*)(scratch + (size_t)a * N);
    float v[32];
#pragma unroll
    for (int s = 0; s < 8; ++s) {
        float4 q = rp[t + 256 * s];
        v[s * 4 + 0] = q.x; v[s * 4 + 1] = q.y; v[s * 4 + 2] = q.z; v[s * 4 + 3] = q.w;
    }
    __shared__ float wsf[4];
    __shared__ int wsi[4];
    unsigned lo = 0u, hi = 0x7F800000u;
    for (int it = 0; it < 32; ++it) {
        if (lo < hi) {
            unsigned mid = (lo + hi) >> 1;
            float mf = __uint_as_float(mid);
            int c = 0;
#pragma unroll
            for (int s = 0; s < 32; ++s) c += (v[s] <= mf) ? 1 : 0;
            for (int off = 32; off; off >>= 1) c += __shfl_down(c, off);
            if ((t & 63) == 0) wsi[t >> 6] = c;
            __syncthreads();
            c = wsi[0] + wsi[1] + wsi[2] + wsi[3];
            __syncthreads();
            if (c >= need) hi = mid; else lo = mid + 1;
        }
    }
    float kvf = __uint_as_float(hi);
    float sum = 0.f; int clt = 0;
#pragma unroll
    for (int s = 0; s < 32; ++s) {
        if (v[s] < kvf) { clt++; sum += sqrtf(v[s]); }
    }
    for (int off = 32; off; off >>= 1) {
        sum += __shfl_down(sum, off);
        clt += __shfl_down(clt, off);
    }
    if ((t & 63) == 0) { wsf[t >> 6] = sum; wsi[t >> 6] = clt; }
    __syncthreads();
    if (t == 0) {
        float sAll = wsf[0] + wsf[1] + wsf[2] + wsf[3];
        int cAll = wsi[0] + wsi[1] + wsi[2] + wsi[3];
        float skv = sqrtf(kvf);
        float aV = skv + 1e-10f;
        float b = sAll + (float)(k - cAll) * skv;
        float denom = aV * (float)k - b + 1e-10f;
        int orig = u_idx[a];
        aArr[orig] = aV;
        dinv[orig] = 1.0f / denom;
    }
}

// final adj fill + sparse part of adj@h for unknown rows
__global__ void k_fill(const float* __restrict__ x, const char* __restrict__ labs,
                       const float* __restrict__ nArr, const float* __restrict__ aArr,
                       const float* __restrict__ dinv, const float* __restrict__ h,
                       const float* __restrict__ scal, float* __restrict__ adj,
                       float* __restrict__ gpre) {
    __shared__ float xi[D];
    __shared__ float red[256];
    int i = blockIdx.x;
    int t = threadIdx.x;
    int li = labs[i];
    float fc = scal[33];
    float* row = adj + (size_t)i * N;
    if (li >= 0) {
        // known row: pure label pattern, write-only
#pragma unroll
        for (int s = 0; s < 8; ++s) {
            int c4 = t + 256 * s;
            char4 l4 = ((const char4*)labs)[c4];
            float4 o;
            o.x = (l4.x < 0) ? fc : ((l4.x == li) ? 1.f : 0.f);
            o.y = (l4.y < 0) ? fc : ((l4.y == li) ? 1.f : 0.f);
            o.z = (l4.z < 0) ? fc : ((l4.z == li) ? 1.f : 0.f);
            o.w = (l4.w < 0) ? fc : ((l4.w == li) ? 1.f : 0.f);
            ((float4*)row)[c4] = o;
        }
        return;
    }
    // unknown row
    if (t < D) xi[t] = x[(size_t)i * D + t];
    __syncthreads();
    float ai = aArr[i], di = dinv[i], ni = nArr[i];
    float s0 = 0.f, s1 = 0.f;
    for (int s = 0; s < 32; ++s) {
        int j = t + 256 * s;
        int lj = labs[j];
        float vout;
        if (lj >= 0) {
            vout = fc;
        } else {
            const float4* xj = (const float4*)(x + (size_t)j * D);
            float dot = 0.f;
#pragma unroll
            for (int q = 0; q < 32; ++q) {
                float4 w = xj[q];
                dot += xi[q * 4 + 0] * w.x + xi[q * 4 + 1] * w.y
                     + xi[q * 4 + 2] * w.z + xi[q * 4 + 3] * w.w;
            }
            float d2 = fmaxf(ni + nArr[j] - 2.f * dot, 0.f);
            float d = sqrtf(d2);
            vout = 0.5f * (fmaxf(ai - d, 0.f) * di + fmaxf(aArr[j] - d, 0.f) * dinv[j]);
            s0 += vout * h[j * 2 + 0];
            s1 += vout * h[j * 2 + 1];
        }
        row[j] = vout;
    }
    red[t] = s0; __syncthreads();
    for (int off = 128; off; off >>= 1) {
        if (t < off) red[t] += red[t + off];
        __syncthreads();
    }
    if (t == 0) gpre[i * 2 + 0] = red[0];
    __syncthreads();
    red[t] = s1; __syncthreads();
    for (int off = 128; off; off >>= 1) {
        if (t < off) red[t] += red[t + off];
        __syncthreads();
    }
    if (t == 0) gpre[i * 2 + 1] = red[0];
}

__global__ void k_g(const char* __restrict__ labs, const float* __restrict__ gpre,
                    const float* __restrict__ scal, float* __restrict__ outg) {
    int i = blockIdx.x * 256 + threadIdx.x;
    if (i >= N) return;
    int li = labs[i];
    float fc = scal[33];
    float g0, g1;
    if (li >= 0) {
        g0 = scal[li * 2 + 0] + fc * scal[20];
        g1 = scal[li * 2 + 1] + fc * scal[21];
    } else {
        g0 = gpre[i * 2 + 0] + fc * scal[34];
        g1 = gpre[i * 2 + 1] + fc * scal[35];
    }
    outg[i * 2 + 0] = tanhf(g0);
    outg[i * 2 + 1] = tanhf(g1);
}

__global__ void k_aggA(const char* __restrict__ labs, const float* __restrict__ g,
                       float* __restrict__ part2) {
    __shared__ float L[256][20];
    int t = threadIdx.x;
    for (int s = 0; s < 20; ++s) L[t][s] = 0.f;
    int row = blockIdx.x * 256 + t;
    if (row < N) {
        int lab = labs[row];
        if (lab >= 0) {
            L[t][lab * 2 + 0] = g[row * 2 + 0];
            L[t][lab * 2 + 1] = g[row * 2 + 1];
        }
    }
    __syncthreads();
    if (t < 20) {
        float s = 0.f;
        for (int i = 0; i < 256; ++i) s += L[i][t];
        part2[blockIdx.x * 20 + t] = s;
    }
}

__global__ void k_aggB(const float* __restrict__ part2, float* __restrict__ scal) {
    int t = threadIdx.x;
    if (t < 20) {
        float s = 0.f;
        for (int i = 0; i < 64; ++i) s += part2[i * 20 + t];
        int c = t >> 1;
        float cnt = scal[22 + c];
        scal[40 + t] = (cnt > 0.f) ? s / fmaxf(cnt, 1.0f) : 0.f;
    }
}

__global__ void k_scores(const float* __restrict__ g, const float* __restrict__ scal,
                         float* __restrict__ outs) {
    int i = blockIdx.x * 256 + threadIdx.x;
    if (i >= N) return;
    float g0 = g[i * 2 + 0], g1 = g[i * 2 + 1];
#pragma unroll
    for (int c = 0; c < NC; ++c) {
        float d0 = g0 - scal[40 + c * 2 + 0];
        float d1 = g1 - scal[40 + c * 2 + 1];
        outs[i * NC + c] = -sqrtf(d0 * d0 + d1 * d1);
    }
}

extern "C" void kernel_launch(void* const* d_in, const int* in_sizes, int n_in,
                              void* d_out, int out_size, void* d_ws, size_t ws_size,
                              hipStream_t stream) {
    const float* x = (const float*)d_in[0];
    const float* ohm = (const float*)d_in[1];
    const float* W = (const float*)d_in[2];
    const float* b = (const float*)d_in[3];
    const int* spars = (const int*)d_in[4];

    float* out = (float*)d_out;
    float* outScores = out;                 // N*NC
    float* outG = out + (size_t)N * NC;     // N*2
    float* adj = outG + (size_t)N * 2;      // N*N (also used as D2 scratch)

    char* wsb = (char*)d_ws;
    int* u_idx   = (int*)(wsb + 0);
    char* labs   = (char*)(wsb + 32768);
    float* nArr  = (float*)(wsb + 40960);
    float* aArr  = (float*)(wsb + 73728);
    float* dinv  = (float*)(wsb + 106496);
    float* hArr  = (float*)(wsb + 139264);
    float* gpre  = (float*)(wsb + 204800);
    float* part1 = (float*)(wsb + 270336);
    float* part2 = (float*)(wsb + 278784);
    float* scal  = (float*)(wsb + 283904);
    int* nuCnt   = (int*)(wsb + 284160);

    hipMemsetAsync(nuCnt, 0, sizeof(int), stream);
    k_prep<<<2048, 256, 0, stream>>>(x, ohm, W, b, labs, nArr, hArr, u_idx, nuCnt);
    k_sumA<<<64, 256, 0, stream>>>(labs, hArr, part1);
    k_sumB<<<1, 64, 0, stream>>>(part1, scal);
    k_gemm<<<dim3(128, 128), 256, 0, stream>>>(x, nArr, u_idx, nuCnt, adj);
    k_select<<<8192, 256, 0, stream>>>(adj, u_idx, nuCnt, spars, aArr, dinv);
    k_fill<<<8192, 256, 0, stream>>>(x, labs, nArr, aArr, dinv, hArr, scal, adj, gpre);
    k_g<<<32, 256, 0, stream>>>(labs, gpre, scal, outG);
    k_aggA<<<64, 256, 0, stream>>>(labs, outG, part2);
    k_aggB<<<1, 64, 0, stream>>>(part2, scal);
    k_scores<<<32, 256, 0, stream>>>(outG, scal, outScores);
}

// Round 2
// 214.049 us; speedup vs baseline: 2.4772x; 2.4772x over previous
//
#include <hip/hip_runtime.h>
#include <hip/hip_bf16.h>
#include <math.h>

#define N 8192
#define D 128
#define NC 10

// ---------------- ws layout (bytes) ----------------
// 0      : u_idx  int[N]
// 32768  : labs   char[N]
// 40960  : nArr   float[N]
// 73728  : aArr   float[N]
// 106496 : dinv   float[N]
// 139264 : h      float[N*2]
// 204800 : gpre   float[N*2]
// 270336 : part1  float[64*33]
// 278784 : part2  float[64*20]
// 283904 : scal   float[64]
// 284160 : nuCnt  int

__global__ void k_prep(const float* __restrict__ x, const float* __restrict__ ohm,
                       const float* __restrict__ W, const float* __restrict__ bb,
                       char* __restrict__ labs, float* __restrict__ nArr,
                       float* __restrict__ h, int* __restrict__ u_idx,
                       int* __restrict__ nuCnt) {
    int gt = blockIdx.x * blockDim.x + threadIdx.x;
    int wid = gt >> 6;           // one wave per row
    int lane = gt & 63;
    if (wid >= N) return;
    const float2* xr = (const float2*)(x + (size_t)wid * D);
    float2 xv = xr[lane];
    float2 w0 = ((const float2*)W)[lane];
    float2 w1 = ((const float2*)(W + D))[lane];
    float nn = xv.x * xv.x + xv.y * xv.y;
    float h0 = xv.x * w0.x + xv.y * w0.y;
    float h1 = xv.x * w1.x + xv.y * w1.y;
    for (int off = 32; off; off >>= 1) {
        nn += __shfl_down(nn, off);
        h0 += __shfl_down(h0, off);
        h1 += __shfl_down(h1, off);
    }
    if (lane == 0) {
        nArr[wid] = nn;
        h[wid * 2 + 0] = h0 + bb[0];
        h[wid * 2 + 1] = h1 + bb[1];
        const float* orow = ohm + (size_t)wid * NC;
        int lab = -1;
        for (int c = 0; c < NC; ++c) {
            if (orow[c] > 0.5f) { lab = c; break; }
        }
        labs[wid] = (char)lab;
        if (lab < 0) {
            int slot = atomicAdd(nuCnt, 1);
            u_idx[slot] = wid;
        }
    }
}

__global__ void k_sumA(const char* __restrict__ labs, const float* __restrict__ h,
                       float* __restrict__ part1) {
    __shared__ float L[256][33];
    int t = threadIdx.x;
    for (int s = 0; s < 33; ++s) L[t][s] = 0.f;
    int row = blockIdx.x * 256 + t;
    if (row < N) {
        int lab = labs[row];
        float h0 = h[row * 2], h1 = h[row * 2 + 1];
        if (lab >= 0) {
            L[t][lab * 2] = h0; L[t][lab * 2 + 1] = h1; L[t][22 + lab] = 1.f;
        } else {
            L[t][20] = h0; L[t][21] = h1; L[t][32] = 1.f;
        }
    }
    __syncthreads();
    if (t < 33) {
        float s = 0.f;
        for (int i = 0; i < 256; ++i) s += L[i][t];
        part1[blockIdx.x * 33 + t] = s;
    }
}

__global__ void k_sumB(const float* __restrict__ part1, float* __restrict__ scal) {
    int t = threadIdx.x;
    if (t < 33) {
        float s = 0.f;
        for (int i = 0; i < 64; ++i) s += part1[i * 33 + t];
        scal[t] = s;
    }
    __syncthreads();
    if (t == 0) {
        float k0 = 0.f, k1 = 0.f;
        for (int c = 0; c < NC; ++c) { k0 += scal[c * 2]; k1 += scal[c * 2 + 1]; }
        scal[34] = k0; scal[35] = k1;
        scal[33] = 1.0f / fmaxf(scal[32], 1.0f);      // fc
    }
}

// D2[a][j] for unknown rows (compacted), written to adj region as scratch.
__global__ void k_gemm(const float* __restrict__ x, const float* __restrict__ nArr,
                       const int* __restrict__ u_idx, const int* __restrict__ nuCnt,
                       float* __restrict__ scratch) {
    __shared__ float As[64][D + 1];
    __shared__ float Bs[64][D + 1];
    __shared__ int Ai[64];
    int nu = *nuCnt;
    int a0 = blockIdx.y * 64;
    if (a0 >= nu) return;
    int j0 = blockIdx.x * 64;
    int t = threadIdx.x;
    for (int c = t; c < 64 * 32; c += 256) {
        int r = c >> 5, c4 = c & 31;
        int a = a0 + r;
        int orig = (a < nu) ? u_idx[a] : u_idx[0];
        if (c4 == 0) Ai[r] = (a < nu) ? orig : -1;
        float4 av = ((const float4*)(x + (size_t)orig * D))[c4];
        As[r][c4 * 4 + 0] = av.x; As[r][c4 * 4 + 1] = av.y;
        As[r][c4 * 4 + 2] = av.z; As[r][c4 * 4 + 3] = av.w;
        float4 bv = ((const float4*)(x + (size_t)(j0 + r) * D))[c4];
        Bs[r][c4 * 4 + 0] = bv.x; Bs[r][c4 * 4 + 1] = bv.y;
        Bs[r][c4 * 4 + 2] = bv.z; Bs[r][c4 * 4 + 3] = bv.w;
    }
    __syncthreads();
    int tx = t & 15, ty = t >> 4;
    float acc[4][4];
#pragma unroll
    for (int m = 0; m < 4; ++m)
#pragma unroll
        for (int q = 0; q < 4; ++q) acc[m][q] = 0.f;
#pragma unroll 4
    for (int k = 0; k < D; ++k) {
        float a4[4], b4[4];
#pragma unroll
        for (int m = 0; m < 4; ++m) a4[m] = As[ty * 4 + m][k];
#pragma unroll
        for (int q = 0; q < 4; ++q) b4[q] = Bs[tx * 4 + q][k];
#pragma unroll
        for (int m = 0; m < 4; ++m)
#pragma unroll
            for (int q = 0; q < 4; ++q) acc[m][q] += a4[m] * b4[q];
    }
#pragma unroll
    for (int m = 0; m < 4; ++m) {
        int ar = ty * 4 + m;
        int orig = Ai[ar];
        if (orig < 0) continue;
        float ni = nArr[orig];
        float4 o;
        int jb = j0 + tx * 4;
        float v0 = fmaxf(ni + nArr[jb + 0] - 2.f * acc[m][0], 0.f);
        float v1 = fmaxf(ni + nArr[jb + 1] - 2.f * acc[m][1], 0.f);
        float v2 = fmaxf(ni + nArr[jb + 2] - 2.f * acc[m][2], 0.f);
        float v3 = fmaxf(ni + nArr[jb + 3] - 2.f * acc[m][3], 0.f);
        if (orig == jb + 0) v0 = 0.f;
        if (orig == jb + 1) v1 = 0.f;
        if (orig == jb + 2) v2 = 0.f;
        if (orig == jb + 3) v3 = 0.f;
        o.x = v0; o.y = v1; o.z = v2; o.w = v3;
        *((float4*)(scratch + (size_t)(a0 + ar) * N + jb)) = o;
    }
}

// exact kth order statistic per unknown row (bitwise binary search, regs-resident row)
__global__ void k_select(const float* __restrict__ scratch, const int* __restrict__ u_idx,
                         const int* __restrict__ nuCnt, const int* __restrict__ spars,
                         float* __restrict__ aArr, float* __restrict__ dinv) {
    int nu = *nuCnt;
    int a = blockIdx.x;
    if (a >= nu) return;
    int k = *spars;
    int need = k + 1;
    int t = threadIdx.x;
    const float4* rp = (const float4*)(scratch + (size_t)a * N);
    float v[32];
#pragma unroll
    for (int s = 0; s < 8; ++s) {
        float4 q = rp[t + 256 * s];
        v[s * 4 + 0] = q.x; v[s * 4 + 1] = q.y; v[s * 4 + 2] = q.z; v[s * 4 + 3] = q.w;
    }
    __shared__ float wsf[4];
    __shared__ int wsi[4];
    unsigned lo = 0u, hi = 0x7F800000u;
    for (int it = 0; it < 32; ++it) {
        if (lo < hi) {
            unsigned mid = (lo + hi) >> 1;
            float mf = __uint_as_float(mid);
            int c = 0;
#pragma unroll
            for (int s = 0; s < 32; ++s) c += (v[s] <= mf) ? 1 : 0;
            for (int off = 32; off; off >>= 1) c += __shfl_down(c, off);
            if ((t & 63) == 0) wsi[t >> 6] = c;
            __syncthreads();
            c = wsi[0] + wsi[1] + wsi[2] + wsi[3];
            __syncthreads();
            if (c >= need) hi = mid; else lo = mid + 1;
        }
    }
    float kvf = __uint_as_float(hi);
    float sum = 0.f; int clt = 0;
#pragma unroll
    for (int s = 0; s < 32; ++s) {
        if (v[s] < kvf) { clt++; sum += sqrtf(v[s]); }
    }
    for (int off = 32; off; off >>= 1) {
        sum += __shfl_down(sum, off);
        clt += __shfl_down(clt, off);
    }
    if ((t & 63) == 0) { wsf[t >> 6] = sum; wsi[t >> 6] = clt; }
    __syncthreads();
    if (t == 0) {
        float sAll = wsf[0] + wsf[1] + wsf[2] + wsf[3];
        int cAll = wsi[0] + wsi[1] + wsi[2] + wsi[3];
        float skv = sqrtf(kvf);
        float aV = skv + 1e-10f;
        float b = sAll + (float)(k - cAll) * skv;
        float denom = aV * (float)k - b + 1e-10f;
        int orig = u_idx[a];
        aArr[orig] = aV;
        dinv[orig] = 1.0f / denom;
    }
}

// known rows: pure label-pattern writes at full write BW
__global__ void k_fill_known(const char* __restrict__ labs, const float* __restrict__ scal,
                             float* __restrict__ adj) {
    int i = blockIdx.x;
    int li = labs[i];
    if (li < 0) return;
    float fc = scal[33];
    float* row = adj + (size_t)i * N;
    int t = threadIdx.x;
#pragma unroll
    for (int s = 0; s < 8; ++s) {
        int c4 = t + 256 * s;
        char4 l4 = ((const char4*)labs)[c4];
        float4 o;
        o.x = (l4.x < 0) ? fc : ((l4.x == li) ? 1.f : 0.f);
        o.y = (l4.y < 0) ? fc : ((l4.y == li) ? 1.f : 0.f);
        o.z = (l4.z < 0) ? fc : ((l4.z == li) ? 1.f : 0.f);
        o.w = (l4.w < 0) ? fc : ((l4.w == li) ? 1.f : 0.f);
        ((float4*)row)[c4] = o;
    }
}

// unknown rows: LDS-tiled distance recompute fused with adagae epilogue
__global__ void k_fill_unknown(const float* __restrict__ x, const float* __restrict__ nArr,
                               const int* __restrict__ u_idx, const int* __restrict__ nuCnt,
                               const char* __restrict__ labs, const float* __restrict__ aArr,
                               const float* __restrict__ dinv, const float* __restrict__ scal,
                               float* __restrict__ adj) {
    __shared__ float As[64][D + 1];
    __shared__ float Bs[64][D + 1];
    __shared__ int Ai[64];
    int nu = *nuCnt;
    int a0 = blockIdx.y * 64;
    if (a0 >= nu) return;
    int j0 = blockIdx.x * 64;
    int t = threadIdx.x;
    float fc = scal[33];
    for (int c = t; c < 64 * 32; c += 256) {
        int r = c >> 5, c4 = c & 31;
        int a = a0 + r;
        int orig = (a < nu) ? u_idx[a] : u_idx[0];
        if (c4 == 0) Ai[r] = (a < nu) ? orig : -1;
        float4 av = ((const float4*)(x + (size_t)orig * D))[c4];
        As[r][c4 * 4 + 0] = av.x; As[r][c4 * 4 + 1] = av.y;
        As[r][c4 * 4 + 2] = av.z; As[r][c4 * 4 + 3] = av.w;
        float4 bv = ((const float4*)(x + (size_t)(j0 + r) * D))[c4];
        Bs[r][c4 * 4 + 0] = bv.x; Bs[r][c4 * 4 + 1] = bv.y;
        Bs[r][c4 * 4 + 2] = bv.z; Bs[r][c4 * 4 + 3] = bv.w;
    }
    __syncthreads();
    int tx = t & 15, ty = t >> 4;
    float acc[4][4];
#pragma unroll
    for (int m = 0; m < 4; ++m)
#pragma unroll
        for (int q = 0; q < 4; ++q) acc[m][q] = 0.f;
#pragma unroll 4
    for (int k = 0; k < D; ++k) {
        float a4[4], b4[4];
#pragma unroll
        for (int m = 0; m < 4; ++m) a4[m] = As[ty * 4 + m][k];
#pragma unroll
        for (int q = 0; q < 4; ++q) b4[q] = Bs[tx * 4 + q][k];
#pragma unroll
        for (int m = 0; m < 4; ++m)
#pragma unroll
            for (int q = 0; q < 4; ++q) acc[m][q] += a4[m] * b4[q];
    }
#pragma unroll
    for (int m = 0; m < 4; ++m) {
        int ar = ty * 4 + m;
        int orig = Ai[ar];
        if (orig < 0) continue;
        float ni = nArr[orig];
        float ai = aArr[orig], di = dinv[orig];
        int jb = j0 + tx * 4;
        float4 o;
        float* op = (float*)&o;
#pragma unroll
        for (int q = 0; q < 4; ++q) {
            int j = jb + q;
            int lj = labs[j];
            float v;
            if (lj >= 0) {
                v = fc;
            } else {
                float d2 = fmaxf(ni + nArr[j] - 2.f * acc[m][q], 0.f);
                if (orig == j) d2 = 0.f;
                float d = sqrtf(d2);
                v = 0.5f * (fmaxf(ai - d, 0.f) * di + fmaxf(aArr[j] - d, 0.f) * dinv[j]);
            }
            op[q] = v;
        }
        *((float4*)(adj + (size_t)orig * N + jb)) = o;
    }
}

// g_pre for unknown rows = full adj_row . h (reads finished adj)
__global__ void k_gv(const float* __restrict__ adj, const float* __restrict__ h,
                     const int* __restrict__ u_idx, const int* __restrict__ nuCnt,
                     float* __restrict__ gpre) {
    int nu = *nuCnt;
    int a = blockIdx.x;
    if (a >= nu) return;
    int orig = u_idx[a];
    const float4* row = (const float4*)(adj + (size_t)orig * N);
    const float2* h2 = (const float2*)h;
    int t = threadIdx.x;
    float s0 = 0.f, s1 = 0.f;
#pragma unroll
    for (int s = 0; s < 8; ++s) {
        int c4 = t + 256 * s;
        float4 v = row[c4];
        int j = c4 * 4;
        float2 ha = h2[j + 0], hb = h2[j + 1], hc = h2[j + 2], hd = h2[j + 3];
        s0 += v.x * ha.x + v.y * hb.x + v.z * hc.x + v.w * hd.x;
        s1 += v.x * ha.y + v.y * hb.y + v.z * hc.y + v.w * hd.y;
    }
    __shared__ float red[256];
    red[t] = s0; __syncthreads();
    for (int off = 128; off; off >>= 1) {
        if (t < off) red[t] += red[t + off];
        __syncthreads();
    }
    if (t == 0) gpre[orig * 2 + 0] = red[0];
    __syncthreads();
    red[t] = s1; __syncthreads();
    for (int off = 128; off; off >>= 1) {
        if (t < off) red[t] += red[t + off];
        __syncthreads();
    }
    if (t == 0) gpre[orig * 2 + 1] = red[0];
}

__global__ void k_g(const char* __restrict__ labs, const float* __restrict__ gpre,
                    const float* __restrict__ scal, float* __restrict__ outg) {
    int i = blockIdx.x * 256 + threadIdx.x;
    if (i >= N) return;
    int li = labs[i];
    float fc = scal[33];
    float g0, g1;
    if (li >= 0) {
        g0 = scal[li * 2 + 0] + fc * scal[20];
        g1 = scal[li * 2 + 1] + fc * scal[21];
    } else {
        g0 = gpre[i * 2 + 0];
        g1 = gpre[i * 2 + 1];
    }
    outg[i * 2 + 0] = tanhf(g0);
    outg[i * 2 + 1] = tanhf(g1);
}

__global__ void k_aggA(const char* __restrict__ labs, const float* __restrict__ g,
                       float* __restrict__ part2) {
    __shared__ float L[256][20];
    int t = threadIdx.x;
    for (int s = 0; s < 20; ++s) L[t][s] = 0.f;
    int row = blockIdx.x * 256 + t;
    if (row < N) {
        int lab = labs[row];
        if (lab >= 0) {
            L[t][lab * 2 + 0] = g[row * 2 + 0];
            L[t][lab * 2 + 1] = g[row * 2 + 1];
        }
    }
    __syncthreads();
    if (t < 20) {
        float s = 0.f;
        for (int i = 0; i < 256; ++i) s += L[i][t];
        part2[blockIdx.x * 20 + t] = s;
    }
}

__global__ void k_aggB(const float* __restrict__ part2, float* __restrict__ scal) {
    int t = threadIdx.x;
    if (t < 20) {
        float s = 0.f;
        for (int i = 0; i < 64; ++i) s += part2[i * 20 + t];
        int c = t >> 1;
        float cnt = scal[22 + c];
        scal[40 + t] = (cnt > 0.f) ? s / fmaxf(cnt, 1.0f) : 0.f;
    }
}

__global__ void k_scores(const float* __restrict__ g, const float* __restrict__ scal,
                         float* __restrict__ outs) {
    int i = blockIdx.x * 256 + threadIdx.x;
    if (i >= N) return;
    float g0 = g[i * 2 + 0], g1 = g[i * 2 + 1];
#pragma unroll
    for (int c = 0; c < NC; ++c) {
        float d0 = g0 - scal[40 + c * 2 + 0];
        float d1 = g1 - scal[40 + c * 2 + 1];
        outs[i * NC + c] = -sqrtf(d0 * d0 + d1 * d1);
    }
}

extern "C" void kernel_launch(void* const* d_in, const int* in_sizes, int n_in,
                              void* d_out, int out_size, void* d_ws, size_t ws_size,
                              hipStream_t stream) {
    const float* x = (const float*)d_in[0];
    const float* ohm = (const float*)d_in[1];
    const float* W = (const float*)d_in[2];
    const float* b = (const float*)d_in[3];
    const int* spars = (const int*)d_in[4];

    float* out = (float*)d_out;
    float* outScores = out;                 // N*NC
    float* outG = out + (size_t)N * NC;     // N*2
    float* adj = outG + (size_t)N * 2;      // N*N (rows 0..nu-1 used as D2 scratch first)

    char* wsb = (char*)d_ws;
    int* u_idx   = (int*)(wsb + 0);
    char* labs   = (char*)(wsb + 32768);
    float* nArr  = (float*)(wsb + 40960);
    float* aArr  = (float*)(wsb + 73728);
    float* dinv  = (float*)(wsb + 106496);
    float* hArr  = (float*)(wsb + 139264);
    float* gpre  = (float*)(wsb + 204800);
    float* part1 = (float*)(wsb + 270336);
    float* part2 = (float*)(wsb + 278784);
    float* scal  = (float*)(wsb + 283904);
    int* nuCnt   = (int*)(wsb + 284160);

    hipMemsetAsync(nuCnt, 0, sizeof(int), stream);
    k_prep<<<2048, 256, 0, stream>>>(x, ohm, W, b, labs, nArr, hArr, u_idx, nuCnt);
    k_sumA<<<64, 256, 0, stream>>>(labs, hArr, part1);
    k_sumB<<<1, 64, 0, stream>>>(part1, scal);
    k_gemm<<<dim3(128, 128), 256, 0, stream>>>(x, nArr, u_idx, nuCnt, adj);
    k_select<<<8192, 256, 0, stream>>>(adj, u_idx, nuCnt, spars, aArr, dinv);
    k_fill_known<<<8192, 256, 0, stream>>>(labs, scal, adj);
    k_fill_unknown<<<dim3(128, 128), 256, 0, stream>>>(x, nArr, u_idx, nuCnt, labs,
                                                       aArr, dinv, scal, adj);
    k_gv<<<8192, 256, 0, stream>>>(adj, hArr, u_idx, nuCnt, gpre);
    k_g<<<32, 256, 0, stream>>>(labs, gpre, scal, outG);
    k_aggA<<<64, 256, 0, stream>>>(labs, outG, part2);
    k_aggB<<<1, 64, 0, stream>>>(part2, scal);
    k_scores<<<32, 256, 0, stream>>>(outG, scal, outScores);
}

// Round 3
// 193.001 us; speedup vs baseline: 2.7473x; 1.1091x over previous
//
#include <hip/hip_runtime.h>
#include <hip/hip_bf16.h>
#include <math.h>

#define N 8192
#define D 128
#define NC 10

typedef float f4 __attribute__((ext_vector_type(4)));

__device__ __forceinline__ void nt_store4(float* p, float a, float b, float c, float d) {
    f4 v; v[0] = a; v[1] = b; v[2] = c; v[3] = d;
    __builtin_nontemporal_store(v, (f4*)p);
}

// ---------------- ws layout (bytes) ----------------
// 0       : u_idx  int[N]
// 32768   : labs   char[N]
// 40960   : nArr   float[N]
// 73728   : aArr   float[N]
// 106496  : dinv   float[N]
// 139264  : h      float[N*2]
// 204800  : gpre   float[N*2]
// 270336  : part1  float[64*33]
// 278784  : part2  float[32*20]
// 283904  : scal   float[64]
// 284160  : nuCnt  int
// 524288  : gp     float[nu*8]     (per (row, j-chunk) partial adj.h sums, fast path)
// 2097152 : d2     float[cap*N]    (compacted squared distances, fast path)

__global__ void k_zero(int* __restrict__ p) {
    if (threadIdx.x == 0) *p = 0;
}

__global__ void k_prep(const float* __restrict__ x, const float* __restrict__ ohm,
                       const float* __restrict__ W, const float* __restrict__ bb,
                       char* __restrict__ labs, float* __restrict__ nArr,
                       float* __restrict__ h, int* __restrict__ u_idx,
                       int* __restrict__ nuCnt) {
    int gt = blockIdx.x * blockDim.x + threadIdx.x;
    int wid = gt >> 6;           // one wave per row
    int lane = gt & 63;
    if (wid >= N) return;
    const float2* xr = (const float2*)(x + (size_t)wid * D);
    float2 xv = xr[lane];
    float2 w0 = ((const float2*)W)[lane];
    float2 w1 = ((const float2*)(W + D))[lane];
    float nn = xv.x * xv.x + xv.y * xv.y;
    float h0 = xv.x * w0.x + xv.y * w0.y;
    float h1 = xv.x * w1.x + xv.y * w1.y;
    for (int off = 32; off; off >>= 1) {
        nn += __shfl_down(nn, off);
        h0 += __shfl_down(h0, off);
        h1 += __shfl_down(h1, off);
    }
    if (lane == 0) {
        nArr[wid] = nn;
        h[wid * 2 + 0] = h0 + bb[0];
        h[wid * 2 + 1] = h1 + bb[1];
        const float* orow = ohm + (size_t)wid * NC;
        int lab = -1;
        for (int c = 0; c < NC; ++c) {
            if (orow[c] > 0.5f) { lab = c; break; }
        }
        labs[wid] = (char)lab;
        if (lab < 0) {
            int slot = atomicAdd(nuCnt, 1);
            u_idx[slot] = wid;
        }
    }
}

__global__ void k_sumA(const char* __restrict__ labs, const float* __restrict__ h,
                       float* __restrict__ part1) {
    __shared__ float L[256][33];
    int t = threadIdx.x;
    for (int s = 0; s < 33; ++s) L[t][s] = 0.f;
    int row = blockIdx.x * 256 + t;
    if (row < N) {
        int lab = labs[row];
        float h0 = h[row * 2], h1 = h[row * 2 + 1];
        if (lab >= 0) {
            L[t][lab * 2] = h0; L[t][lab * 2 + 1] = h1; L[t][22 + lab] = 1.f;
        } else {
            L[t][20] = h0; L[t][21] = h1; L[t][32] = 1.f;
        }
    }
    __syncthreads();
    if (t < 33) {
        float s = 0.f;
        for (int i = 0; i < 256; ++i) s += L[i][t];
        part1[blockIdx.x * 33 + t] = s;
    }
}

__global__ void k_sumB(const float* __restrict__ part1, float* __restrict__ scal) {
    int t = threadIdx.x;
    if (t < 33) {
        float s = 0.f;
        for (int i = 0; i < 64; ++i) s += part1[i * 33 + t];
        scal[t] = s;
    }
    __syncthreads();
    if (t == 0) {
        scal[33] = 1.0f / fmaxf(scal[32], 1.0f);      // fc
    }
}

// D2[a][j] for unknown rows (compacted). dst = ws d2 (fast) or adj (fallback).
__global__ void k_gemm(const float* __restrict__ x, const float* __restrict__ nArr,
                       const int* __restrict__ u_idx, const int* __restrict__ nuCnt,
                       int cap, float* __restrict__ d2a, float* __restrict__ adj) {
    __shared__ float As[64][D + 1];
    __shared__ float Bs[64][D + 1];
    __shared__ int Ai[64];
    int nu = *nuCnt;
    float* dst = (nu <= cap) ? d2a : adj;
    int a0 = blockIdx.y * 64;
    if (a0 >= nu) return;
    int j0 = blockIdx.x * 64;
    int t = threadIdx.x;
    for (int c = t; c < 64 * 32; c += 256) {
        int r = c >> 5, c4 = c & 31;
        int a = a0 + r;
        int orig = (a < nu) ? u_idx[a] : u_idx[0];
        if (c4 == 0) Ai[r] = (a < nu) ? orig : -1;
        float4 av = ((const float4*)(x + (size_t)orig * D))[c4];
        As[r][c4 * 4 + 0] = av.x; As[r][c4 * 4 + 1] = av.y;
        As[r][c4 * 4 + 2] = av.z; As[r][c4 * 4 + 3] = av.w;
        float4 bv = ((const float4*)(x + (size_t)(j0 + r) * D))[c4];
        Bs[r][c4 * 4 + 0] = bv.x; Bs[r][c4 * 4 + 1] = bv.y;
        Bs[r][c4 * 4 + 2] = bv.z; Bs[r][c4 * 4 + 3] = bv.w;
    }
    __syncthreads();
    int tx = t & 15, ty = t >> 4;
    float acc[4][4];
#pragma unroll
    for (int m = 0; m < 4; ++m)
#pragma unroll
        for (int q = 0; q < 4; ++q) acc[m][q] = 0.f;
#pragma unroll 4
    for (int k = 0; k < D; ++k) {
        float a4[4], b4[4];
#pragma unroll
        for (int m = 0; m < 4; ++m) a4[m] = As[ty * 4 + m][k];
#pragma unroll
        for (int q = 0; q < 4; ++q) b4[q] = Bs[tx * 4 + q][k];
#pragma unroll
        for (int m = 0; m < 4; ++m)
#pragma unroll
            for (int q = 0; q < 4; ++q) acc[m][q] += a4[m] * b4[q];
    }
#pragma unroll
    for (int m = 0; m < 4; ++m) {
        int ar = ty * 4 + m;
        int orig = Ai[ar];
        if (orig < 0) continue;
        float ni = nArr[orig];
        int jb = j0 + tx * 4;
        float v0 = fmaxf(ni + nArr[jb + 0] - 2.f * acc[m][0], 0.f);
        float v1 = fmaxf(ni + nArr[jb + 1] - 2.f * acc[m][1], 0.f);
        float v2 = fmaxf(ni + nArr[jb + 2] - 2.f * acc[m][2], 0.f);
        float v3 = fmaxf(ni + nArr[jb + 3] - 2.f * acc[m][3], 0.f);
        if (orig == jb + 0) v0 = 0.f;
        if (orig == jb + 1) v1 = 0.f;
        if (orig == jb + 2) v2 = 0.f;
        if (orig == jb + 3) v3 = 0.f;
        float4 o; o.x = v0; o.y = v1; o.z = v2; o.w = v3;
        *((float4*)(dst + (size_t)(a0 + ar) * N + jb)) = o;
    }
}

// exact kth order statistic per unknown row (bitwise binary search, regs-resident row)
__global__ void k_select(const float* __restrict__ d2a, const float* __restrict__ adj,
                         const int* __restrict__ u_idx, const int* __restrict__ nuCnt,
                         int cap, const int* __restrict__ spars,
                         float* __restrict__ aArr, float* __restrict__ dinv) {
    int nu = *nuCnt;
    int a = blockIdx.x;
    if (a >= nu) return;
    const float* src = (nu <= cap) ? d2a : adj;
    int k = *spars;
    int need = k + 1;
    int t = threadIdx.x;
    const float4* rp = (const float4*)(src + (size_t)a * N);
    float v[32];
#pragma unroll
    for (int s = 0; s < 8; ++s) {
        float4 q = rp[t + 256 * s];
        v[s * 4 + 0] = q.x; v[s * 4 + 1] = q.y; v[s * 4 + 2] = q.z; v[s * 4 + 3] = q.w;
    }
    __shared__ float wsf[4];
    __shared__ int wsi[4];
    unsigned lo = 0u, hi = 0x7F800000u;
    for (int it = 0; it < 32; ++it) {
        if (lo < hi) {
            unsigned mid = (lo + hi) >> 1;
            float mf = __uint_as_float(mid);
            int c = 0;
#pragma unroll
            for (int s = 0; s < 32; ++s) c += (v[s] <= mf) ? 1 : 0;
            for (int off = 32; off; off >>= 1) c += __shfl_down(c, off);
            if ((t & 63) == 0) wsi[t >> 6] = c;
            __syncthreads();
            c = wsi[0] + wsi[1] + wsi[2] + wsi[3];
            __syncthreads();
            if (c >= need) hi = mid; else lo = mid + 1;
        }
    }
    float kvf = __uint_as_float(hi);
    float sum = 0.f; int clt = 0;
#pragma unroll
    for (int s = 0; s < 32; ++s) {
        if (v[s] < kvf) { clt++; sum += sqrtf(v[s]); }
    }
    for (int off = 32; off; off >>= 1) {
        sum += __shfl_down(sum, off);
        clt += __shfl_down(clt, off);
    }
    if ((t & 63) == 0) { wsf[t >> 6] = sum; wsi[t >> 6] = clt; }
    __syncthreads();
    if (t == 0) {
        float sAll = wsf[0] + wsf[1] + wsf[2] + wsf[3];
        int cAll = wsi[0] + wsi[1] + wsi[2] + wsi[3];
        float skv = sqrtf(kvf);
        float aV = skv + 1e-10f;
        float b = sAll + (float)(k - cAll) * skv;
        float denom = aV * (float)k - b + 1e-10f;
        int orig = u_idx[a];
        aArr[orig] = aV;
        dinv[orig] = 1.0f / denom;
    }
}

// known rows: pure label-pattern nontemporal writes
__global__ void k_fill_known(const char* __restrict__ labs, const float* __restrict__ scal,
                             float* __restrict__ adj) {
    int i = blockIdx.x;
    int li = labs[i];
    if (li < 0) return;
    float fc = scal[33];
    float* row = adj + (size_t)i * N;
    int t = threadIdx.x;
#pragma unroll
    for (int s = 0; s < 8; ++s) {
        int c4 = t + 256 * s;
        char4 l4 = ((const char4*)labs)[c4];
        float o0 = (l4.x < 0) ? fc : ((l4.x == li) ? 1.f : 0.f);
        float o1 = (l4.y < 0) ? fc : ((l4.y == li) ? 1.f : 0.f);
        float o2 = (l4.z < 0) ? fc : ((l4.z == li) ? 1.f : 0.f);
        float o3 = (l4.w < 0) ? fc : ((l4.w == li) ? 1.f : 0.f);
        nt_store4(row + c4 * 4, o0, o1, o2, o3);
    }
}

// FAST path: unknown rows from stored D2 + fused partial adj.h sums
__global__ void k_fu_fast(const float* __restrict__ d2a, const char* __restrict__ labs,
                          const float* __restrict__ aArr, const float* __restrict__ dinv,
                          const float* __restrict__ h, const float* __restrict__ scal,
                          const int* __restrict__ u_idx, const int* __restrict__ nuCnt,
                          int cap, float* __restrict__ adj, float* __restrict__ gp) {
    int nu = *nuCnt;
    if (nu > cap) return;
    int a = blockIdx.y;
    if (a >= nu) return;
    int jc = blockIdx.x;           // 0..3, 2048 cols each
    int t = threadIdx.x;
    int orig = u_idx[a];
    float fc = scal[33];
    float ai = aArr[orig], di = dinv[orig];
    const float* drow = d2a + (size_t)a * N;
    float* orow = adj + (size_t)orig * N;
    const float2* h2 = (const float2*)h;
    float s0 = 0.f, s1 = 0.f;
#pragma unroll
    for (int s = 0; s < 2; ++s) {
        int c4 = jc * 512 + s * 256 + t;   // float4 index
        int j = c4 * 4;
        float4 dv = ((const float4*)drow)[c4];
        char4 l4 = ((const char4*)labs)[c4];
        float dd[4] = {dv.x, dv.y, dv.z, dv.w};
        signed char ll[4] = {(signed char)l4.x, (signed char)l4.y,
                             (signed char)l4.z, (signed char)l4.w};
        float v[4];
#pragma unroll
        for (int q = 0; q < 4; ++q) {
            if (ll[q] >= 0) {
                v[q] = fc;
            } else {
                float d = sqrtf(dd[q]);
                v[q] = 0.5f * (fmaxf(ai - d, 0.f) * di + fmaxf(aArr[j + q] - d, 0.f) * dinv[j + q]);
            }
            float2 hh = h2[j + q];
            s0 += v[q] * hh.x;
            s1 += v[q] * hh.y;
        }
        nt_store4(orow + j, v[0], v[1], v[2], v[3]);
    }
    __shared__ float red[256];
    red[t] = s0; __syncthreads();
    for (int off = 128; off; off >>= 1) {
        if (t < off) red[t] += red[t + off];
        __syncthreads();
    }
    float r0 = red[0];
    __syncthreads();
    red[t] = s1; __syncthreads();
    for (int off = 128; off; off >>= 1) {
        if (t < off) red[t] += red[t + off];
        __syncthreads();
    }
    if (t == 0) { gp[a * 8 + jc * 2 + 0] = r0; gp[a * 8 + jc * 2 + 1] = red[0]; }
}

__global__ void k_gred(const float* __restrict__ gp, const int* __restrict__ u_idx,
                       const int* __restrict__ nuCnt, int cap, float* __restrict__ gpre) {
    int nu = *nuCnt;
    if (nu > cap) return;
    int a = blockIdx.x * 256 + threadIdx.x;
    if (a >= nu) return;
    int orig = u_idx[a];
    float s0 = 0.f, s1 = 0.f;
    for (int jc = 0; jc < 4; ++jc) {
        s0 += gp[a * 8 + jc * 2 + 0];
        s1 += gp[a * 8 + jc * 2 + 1];
    }
    gpre[orig * 2 + 0] = s0;
    gpre[orig * 2 + 1] = s1;
}

// FALLBACK path (nu > cap): recompute distances tiled, normal stores
__global__ void k_fu_slow(const float* __restrict__ x, const float* __restrict__ nArr,
                          const int* __restrict__ u_idx, const int* __restrict__ nuCnt,
                          int cap, const char* __restrict__ labs,
                          const float* __restrict__ aArr, const float* __restrict__ dinv,
                          const float* __restrict__ scal, float* __restrict__ adj) {
    __shared__ float As[64][D + 1];
    __shared__ float Bs[64][D + 1];
    __shared__ int Ai[64];
    int nu = *nuCnt;
    if (nu <= cap) return;
    int a0 = blockIdx.y * 64;
    if (a0 >= nu) return;
    int j0 = blockIdx.x * 64;
    int t = threadIdx.x;
    float fc = scal[33];
    for (int c = t; c < 64 * 32; c += 256) {
        int r = c >> 5, c4 = c & 31;
        int a = a0 + r;
        int orig = (a < nu) ? u_idx[a] : u_idx[0];
        if (c4 == 0) Ai[r] = (a < nu) ? orig : -1;
        float4 av = ((const float4*)(x + (size_t)orig * D))[c4];
        As[r][c4 * 4 + 0] = av.x; As[r][c4 * 4 + 1] = av.y;
        As[r][c4 * 4 + 2] = av.z; As[r][c4 * 4 + 3] = av.w;
        float4 bv = ((const float4*)(x + (size_t)(j0 + r) * D))[c4];
        Bs[r][c4 * 4 + 0] = bv.x; Bs[r][c4 * 4 + 1] = bv.y;
        Bs[r][c4 * 4 + 2] = bv.z; Bs[r][c4 * 4 + 3] = bv.w;
    }
    __syncthreads();
    int tx = t & 15, ty = t >> 4;
    float acc[4][4];
#pragma unroll
    for (int m = 0; m < 4; ++m)
#pragma unroll
        for (int q = 0; q < 4; ++q) acc[m][q] = 0.f;
#pragma unroll 4
    for (int k = 0; k < D; ++k) {
        float a4[4], b4[4];
#pragma unroll
        for (int m = 0; m < 4; ++m) a4[m] = As[ty * 4 + m][k];
#pragma unroll
        for (int q = 0; q < 4; ++q) b4[q] = Bs[tx * 4 + q][k];
#pragma unroll
        for (int m = 0; m < 4; ++m)
#pragma unroll
            for (int q = 0; q < 4; ++q) acc[m][q] += a4[m] * b4[q];
    }
#pragma unroll
    for (int m = 0; m < 4; ++m) {
        int ar = ty * 4 + m;
        int orig = Ai[ar];
        if (orig < 0) continue;
        float ni = nArr[orig];
        float ai = aArr[orig], di = dinv[orig];
        int jb = j0 + tx * 4;
        float4 o;
        float* op = (float*)&o;
#pragma unroll
        for (int q = 0; q < 4; ++q) {
            int j = jb + q;
            int lj = labs[j];
            float v;
            if (lj >= 0) {
                v = fc;
            } else {
                float d2 = fmaxf(ni + nArr[j] - 2.f * acc[m][q], 0.f);
                if (orig == j) d2 = 0.f;
                float d = sqrtf(d2);
                v = 0.5f * (fmaxf(ai - d, 0.f) * di + fmaxf(aArr[j] - d, 0.f) * dinv[j]);
            }
            op[q] = v;
        }
        *((float4*)(adj + (size_t)orig * N + jb)) = o;
    }
}

// FALLBACK: g_pre for unknown rows = full adj_row . h
__global__ void k_gv(const float* __restrict__ adj, const float* __restrict__ h,
                     const int* __restrict__ u_idx, const int* __restrict__ nuCnt,
                     int cap, float* __restrict__ gpre) {
    int nu = *nuCnt;
    if (nu <= cap) return;
    int a = blockIdx.x;
    if (a >= nu) return;
    int orig = u_idx[a];
    const float4* row = (const float4*)(adj + (size_t)orig * N);
    const float2* h2 = (const float2*)h;
    int t = threadIdx.x;
    float s0 = 0.f, s1 = 0.f;
#pragma unroll
    for (int s = 0; s < 8; ++s) {
        int c4 = t + 256 * s;
        float4 v = row[c4];
        int j = c4 * 4;
        float2 ha = h2[j + 0], hb = h2[j + 1], hc = h2[j + 2], hd = h2[j + 3];
        s0 += v.x * ha.x + v.y * hb.x + v.z * hc.x + v.w * hd.x;
        s1 += v.x * ha.y + v.y * hb.y + v.z * hc.y + v.w * hd.y;
    }
    __shared__ float red[256];
    red[t] = s0; __syncthreads();
    for (int off = 128; off; off >>= 1) {
        if (t < off) red[t] += red[t + off];
        __syncthreads();
    }
    if (t == 0) gpre[orig * 2 + 0] = red[0];
    __syncthreads();
    red[t] = s1; __syncthreads();
    for (int off = 128; off; off >>= 1) {
        if (t < off) red[t] += red[t + off];
        __syncthreads();
    }
    if (t == 0) gpre[orig * 2 + 1] = red[0];
}

// g = tanh(g_pre), write outG, and per-block label partial sums of g
__global__ void k_gagg(const char* __restrict__ labs, const float* __restrict__ gpre,
                       const float* __restrict__ scal, float* __restrict__ outg,
                       float* __restrict__ part2) {
    __shared__ float L[256][21];
    int t = threadIdx.x;
    for (int s = 0; s < 20; ++s) L[t][s] = 0.f;
    int i = blockIdx.x * 256 + t;
    int li = labs[i];
    float fc = scal[33];
    float g0, g1;
    if (li >= 0) {
        g0 = scal[li * 2 + 0] + fc * scal[20];
        g1 = scal[li * 2 + 1] + fc * scal[21];
    } else {
        g0 = gpre[i * 2 + 0];
        g1 = gpre[i * 2 + 1];
    }
    g0 = tanhf(g0); g1 = tanhf(g1);
    outg[i * 2 + 0] = g0;
    outg[i * 2 + 1] = g1;
    if (li >= 0) { L[t][li * 2 + 0] = g0; L[t][li * 2 + 1] = g1; }
    __syncthreads();
    if (t < 20) {
        float s = 0.f;
        for (int r = 0; r < 256; ++r) s += L[r][t];
        part2[blockIdx.x * 20 + t] = s;
    }
}

__global__ void k_aggB(const float* __restrict__ part2, float* __restrict__ scal) {
    int t = threadIdx.x;
    if (t < 20) {
        float s = 0.f;
        for (int i = 0; i < 32; ++i) s += part2[i * 20 + t];
        int c = t >> 1;
        float cnt = scal[22 + c];
        scal[40 + t] = (cnt > 0.f) ? s / fmaxf(cnt, 1.0f) : 0.f;
    }
}

__global__ void k_scores(const float* __restrict__ g, const float* __restrict__ scal,
                         float* __restrict__ outs) {
    int i = blockIdx.x * 256 + threadIdx.x;
    if (i >= N) return;
    float g0 = g[i * 2 + 0], g1 = g[i * 2 + 1];
#pragma unroll
    for (int c = 0; c < NC; ++c) {
        float d0 = g0 - scal[40 + c * 2 + 0];
        float d1 = g1 - scal[40 + c * 2 + 1];
        outs[i * NC + c] = -sqrtf(d0 * d0 + d1 * d1);
    }
}

extern "C" void kernel_launch(void* const* d_in, const int* in_sizes, int n_in,
                              void* d_out, int out_size, void* d_ws, size_t ws_size,
                              hipStream_t stream) {
    const float* x = (const float*)d_in[0];
    const float* ohm = (const float*)d_in[1];
    const float* W = (const float*)d_in[2];
    const float* b = (const float*)d_in[3];
    const int* spars = (const int*)d_in[4];

    float* out = (float*)d_out;
    float* outScores = out;                 // N*NC
    float* outG = out + (size_t)N * NC;     // N*2
    float* adj = outG + (size_t)N * 2;      // N*N

    char* wsb = (char*)d_ws;
    int* u_idx   = (int*)(wsb + 0);
    char* labs   = (char*)(wsb + 32768);
    float* nArr  = (float*)(wsb + 40960);
    float* aArr  = (float*)(wsb + 73728);
    float* dinv  = (float*)(wsb + 106496);
    float* hArr  = (float*)(wsb + 139264);
    float* gpre  = (float*)(wsb + 204800);
    float* part1 = (float*)(wsb + 270336);
    float* part2 = (float*)(wsb + 278784);
    float* scal  = (float*)(wsb + 283904);
    int* nuCnt   = (int*)(wsb + 284160);
    float* gp    = (float*)(wsb + 524288);
    float* d2a   = (float*)(wsb + 2097152);

    // capacity (rows of N floats) available for D2 in ws beyond 2 MB
    long capL = ((long)ws_size - 2097152L) / ((long)N * 4);
    if (capL < 0) capL = 0;
    if (capL > N) capL = N;
    int cap = (int)capL;

    k_zero<<<1, 64, 0, stream>>>(nuCnt);
    k_prep<<<2048, 256, 0, stream>>>(x, ohm, W, b, labs, nArr, hArr, u_idx, nuCnt);
    k_sumA<<<64, 256, 0, stream>>>(labs, hArr, part1);
    k_sumB<<<1, 64, 0, stream>>>(part1, scal);
    k_gemm<<<dim3(128, 128), 256, 0, stream>>>(x, nArr, u_idx, nuCnt, cap, d2a, adj);
    k_select<<<8192, 256, 0, stream>>>(d2a, adj, u_idx, nuCnt, cap, spars, aArr, dinv);
    k_fill_known<<<8192, 256, 0, stream>>>(labs, scal, adj);
    k_fu_fast<<<dim3(4, 8192), 256, 0, stream>>>(d2a, labs, aArr, dinv, hArr, scal,
                                                 u_idx, nuCnt, cap, adj, gp);
    k_fu_slow<<<dim3(128, 128), 256, 0, stream>>>(x, nArr, u_idx, nuCnt, cap, labs,
                                                  aArr, dinv, scal, adj);
    k_gred<<<32, 256, 0, stream>>>(gp, u_idx, nuCnt, cap, gpre);
    k_gv<<<8192, 256, 0, stream>>>(adj, hArr, u_idx, nuCnt, cap, gpre);
    k_gagg<<<32, 256, 0, stream>>>(labs, gpre, scal, outG, part2);
    k_aggB<<<1, 64, 0, stream>>>(part2, scal);
    k_scores<<<32, 256, 0, stream>>>(outG, scal, outScores);
}